// Round 17
// baseline (396.707 us; speedup 1.0000x reference)
//
#include <hip/hip_runtime.h>

// DiffAttnLayer: B=2,N=2048,EMB=1024,H=8,HD=64,FF=4096.
// Inputs fp32 (runtime-detected); output dtype follows input dtype.
// R25 = R24 (best passing 394.9us; merged FFN) + attn softmax overflow-guard:
// the row-max reduce (15 fmax + 2 shfl + ballot, the last serial cross-lane
// chain per tile) exists only as an overflow guard — softmax is
// scale-invariant under a fixed shift. Replace with a post-hoc check
// ps > 1e18 (1 cmp + ballot); in-dist ps <= ~1e5 so it never fires. Rare
// branch computes the true max, rescales oacc/lst, recomputes p (safe for
// adversarial data; p finite for s<88, guard margin ~1e20 below f32 max).
// Workspace (merged): A h1/ob/h2 | B q | C k | D vT->WoT->W1T(full) |
//  E WqkvT->x2 | g@40MB(32MB) | W2T@72MB(8MB) | lam/flag@80MB

typedef unsigned short u16;
typedef unsigned int u32;
typedef __attribute__((ext_vector_type(8))) __bf16 bf16x8;
typedef __attribute__((ext_vector_type(4))) float f32x4;
typedef __attribute__((ext_vector_type(4))) u32 u32x4;
typedef __attribute__((ext_vector_type(2))) u32 u32x2;

#define LOG2E 1.4426950408889634f
#define LAM_INIT 0.355509068f
#define ONE_MINUS_LAM_INIT 0.644490932f

__device__ __forceinline__ float bf2f(u16 x) {
  u32 u = ((u32)x) << 16;
  return __builtin_bit_cast(float, u);
}
__device__ __forceinline__ u16 f2bf(float f) {
  u32 u = __builtin_bit_cast(u32, f);
  u32 r = (u + 0x7FFFu + ((u >> 16) & 1u)) >> 16;
  return (u16)r;
}
__device__ __forceinline__ u32 cvtpk(float lo, float hi) {
  u32 r;
  asm("v_cvt_pk_bf16_f32 %0, %1, %2" : "=v"(r) : "v"(lo), "v"(hi));
  return r;
}
// raw hardware exp2 (v_exp_f32): 1 instr on the TRANS pipe (libm exp2f is ~6-8)
__device__ __forceinline__ float fexp2(float x) {
  float r;
  asm("v_exp_f32 %0, %1" : "=v"(r) : "v"(x));
  return r;
}
__device__ __forceinline__ float ldf(const void* p, size_t i, bool f32) {
  return f32 ? ((const float*)p)[i] : bf2f(((const u16*)p)[i]);
}
// global -> LDS async DMA, 16B/lane; LDS dest = wave-uniform base + lane*16.
__device__ __forceinline__ void async16(const u16* g, u16* l) {
  __builtin_amdgcn_global_load_lds((const __attribute__((address_space(1))) u32*)g,
                                   (__attribute__((address_space(3))) u32*)l, 16, 0, 0);
}
__device__ __forceinline__ bf16x8 ld8(const u16* p) { return *(const bf16x8*)p; }

// ---------------- input-dtype detector (1 = bf16, 0 = fp32) ----------------
__global__ void detect_kernel(const u32* x, int* flag) {
  int e = (x[threadIdx.x] >> 7) & 0xFF;
  unsigned long long m = __ballot(e >= 90 && e <= 150);
  if (threadIdx.x == 0) flag[0] = (__popcll(m) >= 40) ? 1 : 0;
}

// ---------------- lambda ----------------
__global__ void lam_kernel(const void* lq1, const void* lk1, const void* lq2,
                           const void* lk2, const int* flag, float* out) {
  const bool f32 = flag[0] == 0;
  int L = threadIdx.x;
  float a = ldf(lq1, L, f32) * ldf(lk1, L, f32);
  float c = ldf(lq2, L, f32) * ldf(lk2, L, f32);
#pragma unroll
  for (int m = 1; m < 64; m <<= 1) { a += __shfl_xor(a, m); c += __shfl_xor(c, m); }
  if (L == 0) out[0] = __expf(a) - __expf(c) + LAM_INIT;
}

// ---------------- LayerNorm over 1024, one wave per row ----------------
__device__ __forceinline__ void unpack8(u32x4 u, float* f) {
#pragma unroll
  for (int i = 0; i < 4; ++i) {
    f[2 * i] = bf2f((u16)(u[i] & 0xffffu));
    f[2 * i + 1] = bf2f((u16)(u[i] >> 16));
  }
}

template <bool XRAW>
__global__ __launch_bounds__(256) void ln_kernel(const void* __restrict__ x,
                                                 const void* __restrict__ w,
                                                 const void* __restrict__ b,
                                                 const int* __restrict__ flag,
                                                 u16* __restrict__ out) {
  const bool f32 = flag[0] == 0;
  const int row = blockIdx.x * 4 + (threadIdx.x >> 6);
  const int L = threadIdx.x & 63;
  float xv[16];
  if (XRAW && f32) {
    const f32x4* xr = (const f32x4*)((const float*)x + (size_t)row * 1024 + L * 16);
#pragma unroll
    for (int i = 0; i < 4; ++i) {
      f32x4 vv = xr[i];
#pragma unroll
      for (int j = 0; j < 4; ++j) xv[i * 4 + j] = vv[j];
    }
  } else {
    const u16* xr = (const u16*)x + (size_t)row * 1024 + L * 16;
    unpack8(*(const u32x4*)xr, xv);
    unpack8(*(const u32x4*)(xr + 8), xv + 8);
  }
  float s = 0.f, sq = 0.f;
#pragma unroll
  for (int i = 0; i < 16; ++i) { s += xv[i]; sq += xv[i] * xv[i]; }
#pragma unroll
  for (int m = 1; m < 64; m <<= 1) { s += __shfl_xor(s, m); sq += __shfl_xor(sq, m); }
  float mean = s * (1.0f / 1024.0f);
  float var = sq * (1.0f / 1024.0f) - mean * mean;
  float rstd = rsqrtf(var + 1e-5f);
  u32 pk[8];
#pragma unroll
  for (int i = 0; i < 8; ++i) {
    float w0 = ldf(w, L * 16 + 2 * i, f32), w1 = ldf(w, L * 16 + 2 * i + 1, f32);
    float b0 = ldf(b, L * 16 + 2 * i, f32), b1v = ldf(b, L * 16 + 2 * i + 1, f32);
    float v0 = (xv[2 * i] - mean) * rstd * w0 + b0;
    float v1 = (xv[2 * i + 1] - mean) * rstd * w1 + b1v;
    pk[i] = (u32)f2bf(v0) | ((u32)f2bf(v1) << 16);
  }
  u32x4 o0 = {pk[0], pk[1], pk[2], pk[3]};
  u32x4 o1 = {pk[4], pk[5], pk[6], pk[7]};
  *(u32x4*)(out + (size_t)row * 1024 + L * 16) = o0;
  *(u32x4*)(out + (size_t)row * 1024 + L * 16 + 8) = o1;
}

// -------- transpose+convert: dst[z][c][r] = (bf16)src_z[r][c], z-multiplexed --------
__global__ __launch_bounds__(256) void twc_kernel(const void* __restrict__ s0,
                                                  const void* __restrict__ s1,
                                                  const void* __restrict__ s2,
                                                  u16* __restrict__ dst, int sstride,
                                                  int dstride, size_t soff, size_t dzoff,
                                                  const int* __restrict__ flag) {
  __shared__ __align__(16) u16 tile[64][72];
  const bool f32 = flag[0] == 0;
  const void* src = blockIdx.z == 0 ? s0 : (blockIdx.z == 1 ? s1 : s2);
  u16* dz = dst + (size_t)blockIdx.z * dzoff;
  const int r0 = blockIdx.y * 64, c0 = blockIdx.x * 64;
  const int t = threadIdx.x;
  const int rr = t >> 3, cc = t & 7;
#pragma unroll
  for (int i = 0; i < 2; ++i) {
    int row = rr + i * 32;
    size_t idx = (size_t)(r0 + row) * sstride + c0 + cc * 8 + soff;
    if (f32) {
      const f32x4* s = (const f32x4*)((const float*)src + idx);
      f32x4 a = s[0], b = s[1];
      union { u16 t16[8]; u32x4 v; } u_;
#pragma unroll
      for (int j = 0; j < 4; ++j) { u_.t16[j] = f2bf(a[j]); u_.t16[4 + j] = f2bf(b[j]); }
      *(u32x4*)(&tile[row][cc * 8]) = u_.v;
    } else {
      *(u32x4*)(&tile[row][cc * 8]) = *(const u32x4*)((const u16*)src + idx);
    }
  }
  __syncthreads();
  u16* d = dz + (size_t)c0 * dstride + r0;
#pragma unroll
  for (int i = 0; i < 2; ++i) {
    int n = rr + i * 32;
    union { u16 t16[8]; u32x4 v; } u_;
#pragma unroll
    for (int j = 0; j < 8; ++j) u_.t16[j] = tile[cc * 8 + j][n];
    *(u32x4*)(d + (size_t)n * dstride + cc * 8) = u_.v;
  }
}

// ------------- GEMM: C(MxN) = A(MxK) * Bt(NxK)^T, tile TM x 128 --------------
// Swapped-operand MFMA: acc = mfma(bfr, af) -> lane owns row m = wm+mt*16+l16
// and 4 consecutive cols n = wn+nt*16+quad*4+r. Epilogues use packed stores.
// DB=true: double-buffered LDS, ONE barrier per K-step. DB=false: 2-barrier.
enum { EP_NONE = 0, EP_RES = 2, EP_GELU = 3, EP_BIASRES = 4, EP_QKV = 5 };

template <int TM, int EPI, bool RESRAW, bool OUTFLEX, bool DB>
__global__ __launch_bounds__(256, 2) void gemm_bt(
    const u16* __restrict__ A, const u16* __restrict__ Bt, void* __restrict__ Cv,
    int M, int N, int K, const void* __restrict__ bias, int boff,
    const void* __restrict__ res, const int* __restrict__ flag,
    u16* __restrict__ kout, u16* __restrict__ vtout) {
  constexpr int MT = TM / 32;         // acc tiles per wave in M
  constexpr int HALF = TM * 64 + 128 * 64;  // u16 per buffer
  extern __shared__ __align__(16) u16 lds[];
  const int t = threadIdx.x;
  const int w = t >> 6, L = t & 63;
  const int quad = L >> 4, l16 = L & 15;
  const int m0 = blockIdx.y * TM, n0 = blockIdx.x * 128;
  const int wm = (TM == 128) ? (w >> 1) * 64 : (w & 1) * 32;
  const int wn = (TM == 128) ? (w & 1) * 64 : (w >> 1) * 64;
  const int srow = L >> 3, spc = L & 7;
  const int sc = spc ^ srow;

  f32x4 acc[MT][4] = {};
  const u16* Ab = A + (size_t)m0 * K;
  const u16* Bb = Bt + (size_t)n0 * K;

  auto stage = [&](int kt, int bsel) {
    u16* base = lds + bsel * HALF;
#pragma unroll
    for (int r = 0; r < TM / 32; ++r) {
      int row = r * 32 + w * 8 + srow;
      async16(Ab + (size_t)row * K + kt + sc * 8, &base[row * 64 + spc * 8]);
    }
#pragma unroll
    for (int r = 0; r < 4; ++r) {
      int row = r * 32 + w * 8 + srow;
      async16(Bb + (size_t)row * K + kt + sc * 8, &base[TM * 64 + row * 64 + spc * 8]);
    }
  };
  auto ktile = [&](const u16* base) {
#pragma unroll
    for (int ks = 0; ks < 2; ++ks) {
      bf16x8 af[MT], bfr[4];
#pragma unroll
      for (int mt = 0; mt < MT; ++mt) {
        int row = wm + mt * 16 + l16;
        af[mt] = ld8(&base[row * 64 + (((ks * 4 + quad) ^ (l16 & 7)) * 8)]);
      }
#pragma unroll
      for (int nt = 0; nt < 4; ++nt) {
        int row = wn + nt * 16 + l16;
        bfr[nt] = ld8(&base[TM * 64 + row * 64 + (((ks * 4 + quad) ^ (l16 & 7)) * 8)]);
      }
#pragma unroll
      for (int mt = 0; mt < MT; ++mt)
#pragma unroll
        for (int nt = 0; nt < 4; ++nt)
          acc[mt][nt] =
              __builtin_amdgcn_mfma_f32_16x16x32_bf16(bfr[nt], af[mt], acc[mt][nt], 0, 0, 0);
    }
  };

  if (DB) {
    const int nst = K >> 6;
    stage(0, 0);
    for (int st = 0; st < nst; ++st) {
      __syncthreads();  // drains own DMA(st); all waves done with buf[(st+1)&1]
      if (st + 1 < nst) stage((st + 1) << 6, (st + 1) & 1);
      ktile(lds + (st & 1) * HALF);
    }
  } else {
    for (int kt = 0; kt < K; kt += 64) {
      stage(kt, 0);
      __syncthreads();
      ktile(lds);
      __syncthreads();
    }
  }

  const bool f32 = flag[0] == 0;
#pragma unroll
  for (int mt = 0; mt < MT; ++mt) {
    const int row = m0 + wm + mt * 16 + l16;  // global output row (per lane)
#pragma unroll
    for (int nt = 0; nt < 4; ++nt) {
      const int cb = n0 + wn + nt * 16 + quad * 4;  // 4 consecutive cols
      float v[4];
#pragma unroll
      for (int r = 0; r < 4; ++r) v[r] = acc[mt][nt][r];

      if (EPI == EP_GELU || EPI == EP_BIASRES) {
        float bv[4];
        if (f32) {
          f32x4 bq = *(const f32x4*)((const float*)bias + boff + cb);
#pragma unroll
          for (int r = 0; r < 4; ++r) bv[r] = bq[r];
        } else {
          u32x2 bq = *(const u32x2*)((const u16*)bias + boff + cb);
          bv[0] = bf2f((u16)(bq[0] & 0xffffu));
          bv[1] = bf2f((u16)(bq[0] >> 16));
          bv[2] = bf2f((u16)(bq[1] & 0xffffu));
          bv[3] = bf2f((u16)(bq[1] >> 16));
        }
        if (EPI == EP_GELU) {
#pragma unroll
          for (int r = 0; r < 4; ++r) {
            float x_ = v[r] + bv[r];
            v[r] = 0.5f * x_ * (1.0f + erff(x_ * 0.70710678118654752f));
          }
        } else {
#pragma unroll
          for (int r = 0; r < 4; ++r) v[r] += bv[r];
        }
      }
      if (EPI == EP_RES || EPI == EP_BIASRES) {
        size_t ri = (size_t)row * N + cb;
        if (RESRAW && f32) {
          f32x4 rq = *(const f32x4*)((const float*)res + ri);
#pragma unroll
          for (int r = 0; r < 4; ++r) v[r] += rq[r];
        } else {
          u32x2 rq = *(const u32x2*)((const u16*)res + ri);
          v[0] += bf2f((u16)(rq[0] & 0xffffu));
          v[1] += bf2f((u16)(rq[0] >> 16));
          v[2] += bf2f((u16)(rq[1] & 0xffffu));
          v[3] += bf2f((u16)(rq[1] >> 16));
        }
      }

      if (EPI == EP_QKV) {
        if (cb < 1024) {  // q, pre-scaled by 0.125
          u32x2 pk2 = {cvtpk(v[0] * 0.125f, v[1] * 0.125f),
                       cvtpk(v[2] * 0.125f, v[3] * 0.125f)};
          *(u32x2*)((u16*)Cv + (size_t)row * 1024 + cb) = pk2;
        } else if (cb < 2048) {  // k
          u32x2 pk2 = {cvtpk(v[0], v[1]), cvtpk(v[2], v[3])};
          *(u32x2*)(kout + (size_t)row * 1024 + (cb - 1024)) = pk2;
        } else {  // vT[(b*8+h)*128+d][2048]: d = c2&127 varies with r -> scalar
          int c2 = cb - 2048;
          int bb_ = row >> 11, n = row & 2047, hh = c2 >> 7, d0 = c2 & 127;
#pragma unroll
          for (int r = 0; r < 4; ++r)
            vtout[(size_t)((bb_ * 8 + hh) * 128 + d0 + r) * 2048 + n] = f2bf(v[r]);
        }
      } else {
        size_t ci = (size_t)row * N + cb;
        if (OUTFLEX && f32) {
          f32x4 ov = {v[0], v[1], v[2], v[3]};
          *(f32x4*)((float*)Cv + ci) = ov;
        } else {
          u32x2 pk2 = {cvtpk(v[0], v[1]), cvtpk(v[2], v[3])};
          *(u32x2*)((u16*)Cv + ci) = pk2;
        }
      }
    }
  }
}

// ---------------- Flash differential attention (8-wave, in-register P) ------------
// grid 512 = b(2) x h(8) x qtile(32 of 64 rows), XCD-remapped. 8 waves (512 thr):
// comp=w>>2, rh=(w&3)*16 (16 q-rows per wave). waves/CU 16 (4/SIMD).
// LDS (u16, 64KB dynamic): K[2buf][2comp][64][64] @0 | V[2buf][128][64] @16384
// Q: per-lane direct global loads. P: in-register via cvt_pk + permlane swaps.
// One __syncthreads per tile; K-loop unrolled x2 (compile-time buffer index).
// Softmax: raw v_exp_f32 with FIXED shift (mst=0); the per-tile max reduce is
// replaced by an overflow guard on ps (softmax is scale-invariant under a
// fixed shift; only overflow matters). Guard ps > 1e18 never fires in-dist
// (ps <= ~1e5); rare branch computes true max, rescales, recomputes.
__global__ __launch_bounds__(512, 4) void attn_kernel(
    const u16* __restrict__ q, const u16* __restrict__ k, const u16* __restrict__ vT,
    const float* __restrict__ lamp, const void* __restrict__ subw,
    const int* __restrict__ flag, u16* __restrict__ o) {
  extern __shared__ __align__(16) u16 lds[];
  constexpr int VB = 16384;
  const int t = threadIdx.x, w = t >> 6, L = t & 63;
  const int quad = L >> 4, l16 = L & 15;
  // bijective XCD remap (512 = 8 x 64): XCD x keeps (b,h) pairs {2x,2x+1}
  const int bid = ((blockIdx.x & 7) << 6) | (blockIdx.x >> 3);
  const int qt = bid & 31, h = (bid >> 5) & 7, b = bid >> 8;
  const int q0 = qt * 64;
  const int comp = w >> 2, rh = (w & 3) * 16;
  const int srow = L >> 3, spc = L & 7, sc = spc ^ srow;
  const u16* vb = vT + (size_t)(b * 8 + h) * (128 * 2048);

  auto stageK = [&](int kt, int bsel) {
#pragma unroll
    for (int r = 0; r < 2; ++r) {
      int row = w * 16 + r * 8 + srow;  // 0..127: comp=row>>6, key=row&63
      int c_ = row >> 6, key = row & 63;
      async16(k + ((size_t)(b * 2048 + kt + key) * 1024 + (2 * h + c_) * 64 + sc * 8),
              &lds[bsel * 8192 + row * 64 + spc * 8]);
    }
  };
  auto stageV = [&](int kt, int bsel) {
#pragma unroll
    for (int r = 0; r < 2; ++r) {
      int dim = w * 16 + r * 8 + srow;  // 0..127
      async16(vb + (size_t)dim * 2048 + kt + sc * 8,
              &lds[VB + bsel * 8192 + dim * 64 + spc * 8]);
    }
  };

  stageK(0, 0);
  stageV(0, 0);
  // Q fragments: per-lane direct global loads (one-time; L2-hit). Lane owns
  // qrow = rh + l16 of its comp.
  bf16x8 qf[2];
#pragma unroll
  for (int ks = 0; ks < 2; ++ks) {
    int row = q0 + rh + l16;
    qf[ks] = ld8(q + (size_t)(b * 2048 + row) * 1024 + (2 * h + comp) * 64 +
                 ks * 32 + quad * 8);
  }

  float mst = 0.f, mstl = 0.f, lst = 0.f;
  f32x4 oacc[8] = {};

  // one K/V tile, buffer index bb is a compile-time-foldable constant
  auto tile = [&](int bb) {
    // S^T = Ktile * Q^T for own comp; lane owns qrow = rh + l16
    f32x4 s[4] = {};
#pragma unroll
    for (int ks = 0; ks < 2; ++ks) {
      bf16x8 kf[4];
#pragma unroll
      for (int nt = 0; nt < 4; ++nt) {
        int row = nt * 16 + l16;
        kf[nt] = ld8(&lds[bb * 8192 + comp * 4096 + row * 64 +
                          (((ks * 4 + quad) ^ (l16 & 7)) * 8)]);
      }
#pragma unroll
      for (int nt = 0; nt < 4; ++nt)
        s[nt] = __builtin_amdgcn_mfma_f32_16x16x32_bf16(kf[nt], qf[ks], s[nt], 0, 0, 0);
    }

    // exps with current fixed shift (TRANS pipe; no cross-lane dependency)
    float p[4][4];
#pragma unroll
    for (int nt = 0; nt < 4; ++nt)
#pragma unroll
      for (int r = 0; r < 4; ++r)
        p[nt][r] = fexp2(__builtin_fmaf(s[nt][r], LOG2E, -mstl));

    float ps = 0.f;
#pragma unroll
    for (int nt = 0; nt < 4; ++nt)
#pragma unroll
      for (int r = 0; r < 4; ++r) ps += p[nt][r];

    // overflow guard (replaces the row-max reduce; softmax is shift-invariant)
    if (__ballot(!(ps < 1.0e18f))) {  // wave-uniform; never fires in-dist
      float mx = -3.0e38f;
#pragma unroll
      for (int nt = 0; nt < 4; ++nt)
#pragma unroll
        for (int r = 0; r < 4; ++r) mx = fmaxf(mx, s[nt][r]);
      mx = fmaxf(mx, __shfl_xor(mx, 16));
      mx = fmaxf(mx, __shfl_xor(mx, 32));
      float mnew = fmaxf(mst, mx);
      float al = fexp2((mst - mnew) * LOG2E);
      mst = mnew;
      mstl = mnew * LOG2E;
      lst *= al;
      ps = 0.f;
#pragma unroll
      for (int nt = 0; nt < 4; ++nt)
#pragma unroll
        for (int r = 0; r < 4; ++r) {
          p[nt][r] = fexp2(__builtin_fmaf(s[nt][r], LOG2E, -mstl));
          ps += p[nt][r];
        }
#pragma unroll
      for (int nt = 0; nt < 8; ++nt)
#pragma unroll
        for (int r = 0; r < 4; ++r) oacc[nt][r] *= al;
    }

    u32 wreg[4][2];
#pragma unroll
    for (int nt = 0; nt < 4; ++nt) {
      wreg[nt][0] = cvtpk(p[nt][0], p[nt][1]);
      wreg[nt][1] = cvtpk(p[nt][2], p[nt][3]);
    }
    ps += __shfl_xor(ps, 16);
    ps += __shfl_xor(ps, 32);
    lst += ps;

    // O^T += Vtile^T * P^T ; pf built in-register via permlane swaps
#pragma unroll
    for (int ks = 0; ks < 2; ++ks) {
      u32 a0 = wreg[2 * ks][0], b0 = wreg[2 * ks + 1][0];  // j=0
      u32 a1 = wreg[2 * ks][1], b1 = wreg[2 * ks + 1][1];  // j=1
      asm("v_permlane32_swap_b32 %0, %1" : "+v"(a0), "+v"(b0));
      asm("v_permlane16_swap_b32 %0, %1" : "+v"(a0), "+v"(b0));
      asm("v_permlane32_swap_b32 %0, %1" : "+v"(a1), "+v"(b1));
      asm("v_permlane16_swap_b32 %0, %1" : "+v"(a1), "+v"(b1));
      u32x4 pw = {a0, a1, b0, b1};  // keys base+{0,1},{2,3},{4,5},{6,7}
      bf16x8 pf = __builtin_bit_cast(bf16x8, pw);
#pragma unroll
      for (int nt = 0; nt < 8; ++nt) {
        int dim = nt * 16 + l16;
        bf16x8 vf = ld8(&lds[VB + bb * 8192 + dim * 64 +
                             (((ks * 4 + quad) ^ (l16 & 7)) * 8)]);
        oacc[nt] = __builtin_amdgcn_mfma_f32_16x16x32_bf16(vf, pf, oacc[nt], 0, 0, 0);
      }
    }
  };

  for (int ti = 0; ti < 32; ti += 2) {
    __syncthreads();  // drains own DMA(ti); all waves done reading buf1
    stageK((ti + 1) * 64, 1);
    stageV((ti + 1) * 64, 1);
    tile(0);
    __syncthreads();  // drains own DMA(ti+1); all waves done reading buf0
    if (ti + 2 < 32) {
      stageK((ti + 2) * 64, 0);
      stageV((ti + 2) * 64, 0);
    }
    tile(1);
  }

  // normalize by l (per-lane scalar)
  {
    float inv = 1.0f / lst;
#pragma unroll
    for (int nt = 0; nt < 8; ++nt)
#pragma unroll
      for (int r = 0; r < 4; ++r) oacc[nt][r] *= inv;
  }

  __syncthreads();  // all waves done with K/V -> cb may reuse LDS base
  // combine: comp1 waves dump normalized O2^T (f32x4) to LDS; comp0 diff+RMS+store
  float* cb = (float*)lds;  // 64 rows x 132 floats: cb[qrow][dim] (33.8KB < 64KB)
  if (comp == 1) {
    int rowc = rh + l16;
#pragma unroll
    for (int nt = 0; nt < 8; ++nt)
      *(f32x4*)(&cb[rowc * 132 + nt * 16 + quad * 4]) = oacc[nt];
  }
  __syncthreads();
  if (comp == 0) {
    const bool f32 = flag[0] == 0;
    float lam = lamp[0];
    int rowc = rh + l16;
    float dv[8][4];
    float sq = 0.f;
#pragma unroll
    for (int nt = 0; nt < 8; ++nt) {
      f32x4 c2 = *(const f32x4*)(&cb[rowc * 132 + nt * 16 + quad * 4]);
#pragma unroll
      for (int r = 0; r < 4; ++r) {
        float d = oacc[nt][r] - lam * c2[r];
        dv[nt][r] = d;
        sq += d * d;
      }
    }
    sq += __shfl_xor(sq, 16);
    sq += __shfl_xor(sq, 32);
    float rms = rsqrtf(sq * (1.0f / 128.0f) + 1e-5f);
    size_t rowg = (size_t)(b * 2048 + q0 + rowc) * 1024 + h * 128;
#pragma unroll
    for (int nt = 0; nt < 8; ++nt) {
      float v0 = dv[nt][0] * rms * ldf(subw, nt * 16 + quad * 4 + 0, f32) * ONE_MINUS_LAM_INIT;
      float v1 = dv[nt][1] * rms * ldf(subw, nt * 16 + quad * 4 + 1, f32) * ONE_MINUS_LAM_INIT;
      float v2 = dv[nt][2] * rms * ldf(subw, nt * 16 + quad * 4 + 2, f32) * ONE_MINUS_LAM_INIT;
      float v3 = dv[nt][3] * rms * ldf(subw, nt * 16 + quad * 4 + 3, f32) * ONE_MINUS_LAM_INIT;
      u32x2 pk2 = {cvtpk(v0, v1), cvtpk(v2, v3)};
      *(u32x2*)(o + rowg + nt * 16 + quad * 4) = pk2;
    }
  }
}

// ---------------- host ----------------
extern "C" void kernel_launch(void* const* d_in, const int* in_sizes, int n_in,
                              void* d_out, int out_size, void* d_ws, size_t ws_size,
                              hipStream_t stream) {
  (void)in_sizes; (void)n_in; (void)out_size;
  const void* x = d_in[0];
  const void* ln1w = d_in[1];
  const void* ln1b = d_in[2];
  const void* Wq = d_in[3];
  const void* Wk = d_in[4];
  const void* Wv = d_in[5];
  const void* Wo = d_in[6];
  const void* lq1 = d_in[7];
  const void* lk1 = d_in[8];
  const void* lq2 = d_in[9];
  const void* lk2 = d_in[10];
  const void* subw = d_in[11];
  const void* ln2w = d_in[12];
  const void* ln2b = d_in[13];
  const void* W1 = d_in[14];
  const void* b1 = d_in[15];
  const void* W2 = d_in[16];
  const void* b2 = d_in[17];

  char* ws = (char*)d_ws;
  const size_t MB = 1u << 20;
  u16* A = (u16*)ws;               // h1 -> ob -> h2
  u16* B = (u16*)(ws + 8 * MB);    // q -> g(lo) [fallback]
  u16* C = (u16*)(ws + 16 * MB);   // k -> g(hi) [fallback]
  u16* D = (u16*)(ws + 24 * MB);   // vT -> WoT -> W1T(full or half)|W2Th
  u16* E = (u16*)(ws + 32 * MB);   // WqT|WkT|WvT -> x2
  const bool MERGED = ws_size >= 81 * MB;  // capture-time constant
  u16* gfull = (u16*)(ws + 40 * MB);       // 32MB (merged path)
  u16* W2Tf = (u16*)(ws + 72 * MB);        // 8MB (merged path)
  float* lam = (float*)(MERGED ? ws + 80 * MB : ws + 40 * MB);
  int* flag = (int*)((char*)lam + 64);
  u16* W2Th = D + 2097152;  // fallback per-half W2T (+4MB into D)

  // dynamic-LDS sizes (bytes): gemm HALF = (TM*64 + 128*64)*2
  const int g64_2 = (64 * 64 + 128 * 64) * 2 * 2;   // 49152, double-buffer
  const int g128_2 = (128 * 64 + 128 * 64) * 2 * 2; // 65536, double-buffer

  detect_kernel<<<dim3(1), dim3(64), 0, stream>>>((const u32*)x, flag);
  lam_kernel<<<dim3(1), dim3(64), 0, stream>>>(lq1, lk1, lq2, lk2, flag, lam);
  ln_kernel<true><<<dim3(1024), dim3(256), 0, stream>>>(x, ln1w, ln1b, flag, A);

  // Wq|Wk|Wv -> E concatenated n-major (3072 x 1024)
  twc_kernel<<<dim3(16, 16, 3), dim3(256), 0, stream>>>(Wq, Wk, Wv, E, 1024, 1024, 0,
                                                        1048576, flag);
  // fused q/k/v projection: q->B (pre-scaled), k->C, vT->D
  gemm_bt<128, EP_QKV, false, false, true><<<dim3(24, 32), dim3(256), g128_2, stream>>>(
      A, E, B, 4096, 3072, 1024, nullptr, 0, nullptr, flag, C, D);

  attn_kernel<<<dim3(512), dim3(512), 65536, stream>>>(B, C, D, lam, subw, flag, A);

  // WoT -> D (vT dead); x2(bf16) = ob @ Wo + x -> E (Wq..WvT dead)
  twc_kernel<<<dim3(16, 16, 1), dim3(256), 0, stream>>>(Wo, Wo, Wo, D, 1024, 1024, 0, 0,
                                                        flag);
  gemm_bt<64, EP_RES, true, false, true><<<dim3(8, 64), dim3(256), g64_2, stream>>>(
      A, D, E, 4096, 1024, 1024, nullptr, 0, x, flag, nullptr, nullptr);
  ln_kernel<false><<<dim3(1024), dim3(256), 0, stream>>>(E, ln2w, ln2b, flag, A);

  if (MERGED) {
    // full W1T [4096][1024] -> D (8MB); full W2T [1024][4096] -> W2Tf
    twc_kernel<<<dim3(64, 16, 1), dim3(256), 0, stream>>>(W1, W1, W1, D, 4096, 1024, 0,
                                                          0, flag);
    twc_kernel<<<dim3(16, 64, 1), dim3(256), 0, stream>>>(W2, W2, W2, W2Tf, 1024, 4096,
                                                          0, 0, flag);
    // g = gelu(h2 @ W1 + b1): one full-N launch (M=4096, N=4096, K=1024)
    gemm_bt<128, EP_GELU, false, false, true><<<dim3(32, 32), dim3(256), g128_2,
                                                stream>>>(
        A, D, gfull, 4096, 4096, 1024, b1, 0, nullptr, flag, nullptr, nullptr);
    // out = g @ W2 + b2 + x2: one full-K launch (M=4096, N=1024, K=4096)
    gemm_bt<64, EP_BIASRES, false, true, true><<<dim3(8, 64), dim3(256), g64_2,
                                                 stream>>>(
        gfull, W2Tf, d_out, 4096, 1024, 4096, b2, 0, E, flag, nullptr, nullptr);
  } else {
    // fallback: FFN in two FF-column halves; g = B..C (16MB contiguous)
    for (int hh = 0; hh < 2; ++hh) {
      twc_kernel<<<dim3(32, 16, 1), dim3(256), 0, stream>>>(W1, W1, W1, D, 4096, 1024,
                                                            (size_t)hh * 2048, 0, flag);
      twc_kernel<<<dim3(16, 32, 1), dim3(256), 0, stream>>>(
          W2, W2, W2, W2Th, 1024, 2048, (size_t)hh * 2048 * 1024, 0, flag);
      gemm_bt<128, EP_GELU, false, false, true><<<dim3(16, 32), dim3(256), g128_2,
                                                  stream>>>(
          A, D, B, 4096, 2048, 1024, b1, hh * 2048, nullptr, flag, nullptr, nullptr);
      if (hh == 0) {
        gemm_bt<64, EP_BIASRES, false, true, true><<<dim3(8, 64), dim3(256), g64_2,
                                                     stream>>>(
            B, W2Th, d_out, 4096, 1024, 2048, b2, 0, E, flag, nullptr, nullptr);
      } else {
        gemm_bt<64, EP_RES, true, true, true><<<dim3(8, 64), dim3(256), g64_2,
                                                stream>>>(
            B, W2Th, d_out, 4096, 1024, 2048, nullptr, 0, d_out, flag, nullptr,
            nullptr);
      }
    }
  }
}

// Round 18
// 393.533 us; speedup vs baseline: 1.0081x; 1.0081x over previous
//
#include <hip/hip_runtime.h>

// DiffAttnLayer: B=2,N=2048,EMB=1024,H=8,HD=64,FF=4096.
// Inputs fp32 (runtime-detected); output dtype follows input dtype.
// R26 = R25 (attn overflow-guard softmax, 71us; merged FFN) + 256^2 GELU GEMM:
// M=N=4096 fits grid(16,16)=256 blocks = exactly 1/CU. 512 thr / 8 waves
// (2Mx4N, 128x64/wave), BK=64, 128KB dbuf LDS (hipFuncSetAttribute-gated;
// falls back to TM=128 path on failure). Same proven single-barrier DB
// schedule + XOR swizzle (row stride 128B -> bank-free) + swapped-operand
// epilogue. ds_read:MFMA = 24:64 (m97 ratio), 2x less staging per FLOP.
// Workspace (merged): A h1/ob/h2 | B q | C k | D vT->WoT->W1T(full) |
//  E WqkvT->x2 | g@40MB(32MB) | W2T@72MB(8MB) | lam/flag@80MB

typedef unsigned short u16;
typedef unsigned int u32;
typedef __attribute__((ext_vector_type(8))) __bf16 bf16x8;
typedef __attribute__((ext_vector_type(4))) float f32x4;
typedef __attribute__((ext_vector_type(4))) u32 u32x4;
typedef __attribute__((ext_vector_type(2))) u32 u32x2;

#define LOG2E 1.4426950408889634f
#define LAM_INIT 0.355509068f
#define ONE_MINUS_LAM_INIT 0.644490932f

__device__ __forceinline__ float bf2f(u16 x) {
  u32 u = ((u32)x) << 16;
  return __builtin_bit_cast(float, u);
}
__device__ __forceinline__ u16 f2bf(float f) {
  u32 u = __builtin_bit_cast(u32, f);
  u32 r = (u + 0x7FFFu + ((u >> 16) & 1u)) >> 16;
  return (u16)r;
}
__device__ __forceinline__ u32 cvtpk(float lo, float hi) {
  u32 r;
  asm("v_cvt_pk_bf16_f32 %0, %1, %2" : "=v"(r) : "v"(lo), "v"(hi));
  return r;
}
// raw hardware exp2 (v_exp_f32): 1 instr on the TRANS pipe (libm exp2f is ~6-8)
__device__ __forceinline__ float fexp2(float x) {
  float r;
  asm("v_exp_f32 %0, %1" : "=v"(r) : "v"(x));
  return r;
}
__device__ __forceinline__ float ldf(const void* p, size_t i, bool f32) {
  return f32 ? ((const float*)p)[i] : bf2f(((const u16*)p)[i]);
}
// global -> LDS async DMA, 16B/lane; LDS dest = wave-uniform base + lane*16.
__device__ __forceinline__ void async16(const u16* g, u16* l) {
  __builtin_amdgcn_global_load_lds((const __attribute__((address_space(1))) u32*)g,
                                   (__attribute__((address_space(3))) u32*)l, 16, 0, 0);
}
__device__ __forceinline__ bf16x8 ld8(const u16* p) { return *(const bf16x8*)p; }

// ---------------- input-dtype detector (1 = bf16, 0 = fp32) ----------------
__global__ void detect_kernel(const u32* x, int* flag) {
  int e = (x[threadIdx.x] >> 7) & 0xFF;
  unsigned long long m = __ballot(e >= 90 && e <= 150);
  if (threadIdx.x == 0) flag[0] = (__popcll(m) >= 40) ? 1 : 0;
}

// ---------------- lambda ----------------
__global__ void lam_kernel(const void* lq1, const void* lk1, const void* lq2,
                           const void* lk2, const int* flag, float* out) {
  const bool f32 = flag[0] == 0;
  int L = threadIdx.x;
  float a = ldf(lq1, L, f32) * ldf(lk1, L, f32);
  float c = ldf(lq2, L, f32) * ldf(lk2, L, f32);
#pragma unroll
  for (int m = 1; m < 64; m <<= 1) { a += __shfl_xor(a, m); c += __shfl_xor(c, m); }
  if (L == 0) out[0] = __expf(a) - __expf(c) + LAM_INIT;
}

// ---------------- LayerNorm over 1024, one wave per row ----------------
__device__ __forceinline__ void unpack8(u32x4 u, float* f) {
#pragma unroll
  for (int i = 0; i < 4; ++i) {
    f[2 * i] = bf2f((u16)(u[i] & 0xffffu));
    f[2 * i + 1] = bf2f((u16)(u[i] >> 16));
  }
}

template <bool XRAW>
__global__ __launch_bounds__(256) void ln_kernel(const void* __restrict__ x,
                                                 const void* __restrict__ w,
                                                 const void* __restrict__ b,
                                                 const int* __restrict__ flag,
                                                 u16* __restrict__ out) {
  const bool f32 = flag[0] == 0;
  const int row = blockIdx.x * 4 + (threadIdx.x >> 6);
  const int L = threadIdx.x & 63;
  float xv[16];
  if (XRAW && f32) {
    const f32x4* xr = (const f32x4*)((const float*)x + (size_t)row * 1024 + L * 16);
#pragma unroll
    for (int i = 0; i < 4; ++i) {
      f32x4 vv = xr[i];
#pragma unroll
      for (int j = 0; j < 4; ++j) xv[i * 4 + j] = vv[j];
    }
  } else {
    const u16* xr = (const u16*)x + (size_t)row * 1024 + L * 16;
    unpack8(*(const u32x4*)xr, xv);
    unpack8(*(const u32x4*)(xr + 8), xv + 8);
  }
  float s = 0.f, sq = 0.f;
#pragma unroll
  for (int i = 0; i < 16; ++i) { s += xv[i]; sq += xv[i] * xv[i]; }
#pragma unroll
  for (int m = 1; m < 64; m <<= 1) { s += __shfl_xor(s, m); sq += __shfl_xor(sq, m); }
  float mean = s * (1.0f / 1024.0f);
  float var = sq * (1.0f / 1024.0f) - mean * mean;
  float rstd = rsqrtf(var + 1e-5f);
  u32 pk[8];
#pragma unroll
  for (int i = 0; i < 8; ++i) {
    float w0 = ldf(w, L * 16 + 2 * i, f32), w1 = ldf(w, L * 16 + 2 * i + 1, f32);
    float b0 = ldf(b, L * 16 + 2 * i, f32), b1v = ldf(b, L * 16 + 2 * i + 1, f32);
    float v0 = (xv[2 * i] - mean) * rstd * w0 + b0;
    float v1 = (xv[2 * i + 1] - mean) * rstd * w1 + b1v;
    pk[i] = (u32)f2bf(v0) | ((u32)f2bf(v1) << 16);
  }
  u32x4 o0 = {pk[0], pk[1], pk[2], pk[3]};
  u32x4 o1 = {pk[4], pk[5], pk[6], pk[7]};
  *(u32x4*)(out + (size_t)row * 1024 + L * 16) = o0;
  *(u32x4*)(out + (size_t)row * 1024 + L * 16 + 8) = o1;
}

// -------- transpose+convert: dst[z][c][r] = (bf16)src_z[r][c], z-multiplexed --------
__global__ __launch_bounds__(256) void twc_kernel(const void* __restrict__ s0,
                                                  const void* __restrict__ s1,
                                                  const void* __restrict__ s2,
                                                  u16* __restrict__ dst, int sstride,
                                                  int dstride, size_t soff, size_t dzoff,
                                                  const int* __restrict__ flag) {
  __shared__ __align__(16) u16 tile[64][72];
  const bool f32 = flag[0] == 0;
  const void* src = blockIdx.z == 0 ? s0 : (blockIdx.z == 1 ? s1 : s2);
  u16* dz = dst + (size_t)blockIdx.z * dzoff;
  const int r0 = blockIdx.y * 64, c0 = blockIdx.x * 64;
  const int t = threadIdx.x;
  const int rr = t >> 3, cc = t & 7;
#pragma unroll
  for (int i = 0; i < 2; ++i) {
    int row = rr + i * 32;
    size_t idx = (size_t)(r0 + row) * sstride + c0 + cc * 8 + soff;
    if (f32) {
      const f32x4* s = (const f32x4*)((const float*)src + idx);
      f32x4 a = s[0], b = s[1];
      union { u16 t16[8]; u32x4 v; } u_;
#pragma unroll
      for (int j = 0; j < 4; ++j) { u_.t16[j] = f2bf(a[j]); u_.t16[4 + j] = f2bf(b[j]); }
      *(u32x4*)(&tile[row][cc * 8]) = u_.v;
    } else {
      *(u32x4*)(&tile[row][cc * 8]) = *(const u32x4*)((const u16*)src + idx);
    }
  }
  __syncthreads();
  u16* d = dz + (size_t)c0 * dstride + r0;
#pragma unroll
  for (int i = 0; i < 2; ++i) {
    int n = rr + i * 32;
    union { u16 t16[8]; u32x4 v; } u_;
#pragma unroll
    for (int j = 0; j < 8; ++j) u_.t16[j] = tile[cc * 8 + j][n];
    *(u32x4*)(d + (size_t)n * dstride + cc * 8) = u_.v;
  }
}

// ------------- GEMM: C(MxN) = A(MxK) * Bt(NxK)^T, tile TM x 128 --------------
// Swapped-operand MFMA: acc = mfma(bfr, af) -> lane owns row m = wm+mt*16+l16
// and 4 consecutive cols n = wn+nt*16+quad*4+r. Epilogues use packed stores.
// DB=true: double-buffered LDS, ONE barrier per K-step. DB=false: 2-barrier.
enum { EP_NONE = 0, EP_RES = 2, EP_GELU = 3, EP_BIASRES = 4, EP_QKV = 5 };

template <int TM, int EPI, bool RESRAW, bool OUTFLEX, bool DB>
__global__ __launch_bounds__(256, 2) void gemm_bt(
    const u16* __restrict__ A, const u16* __restrict__ Bt, void* __restrict__ Cv,
    int M, int N, int K, const void* __restrict__ bias, int boff,
    const void* __restrict__ res, const int* __restrict__ flag,
    u16* __restrict__ kout, u16* __restrict__ vtout) {
  constexpr int MT = TM / 32;         // acc tiles per wave in M
  constexpr int HALF = TM * 64 + 128 * 64;  // u16 per buffer
  extern __shared__ __align__(16) u16 lds[];
  const int t = threadIdx.x;
  const int w = t >> 6, L = t & 63;
  const int quad = L >> 4, l16 = L & 15;
  const int m0 = blockIdx.y * TM, n0 = blockIdx.x * 128;
  const int wm = (TM == 128) ? (w >> 1) * 64 : (w & 1) * 32;
  const int wn = (TM == 128) ? (w & 1) * 64 : (w >> 1) * 64;
  const int srow = L >> 3, spc = L & 7;
  const int sc = spc ^ srow;

  f32x4 acc[MT][4] = {};
  const u16* Ab = A + (size_t)m0 * K;
  const u16* Bb = Bt + (size_t)n0 * K;

  auto stage = [&](int kt, int bsel) {
    u16* base = lds + bsel * HALF;
#pragma unroll
    for (int r = 0; r < TM / 32; ++r) {
      int row = r * 32 + w * 8 + srow;
      async16(Ab + (size_t)row * K + kt + sc * 8, &base[row * 64 + spc * 8]);
    }
#pragma unroll
    for (int r = 0; r < 4; ++r) {
      int row = r * 32 + w * 8 + srow;
      async16(Bb + (size_t)row * K + kt + sc * 8, &base[TM * 64 + row * 64 + spc * 8]);
    }
  };
  auto ktile = [&](const u16* base) {
#pragma unroll
    for (int ks = 0; ks < 2; ++ks) {
      bf16x8 af[MT], bfr[4];
#pragma unroll
      for (int mt = 0; mt < MT; ++mt) {
        int row = wm + mt * 16 + l16;
        af[mt] = ld8(&base[row * 64 + (((ks * 4 + quad) ^ (l16 & 7)) * 8)]);
      }
#pragma unroll
      for (int nt = 0; nt < 4; ++nt) {
        int row = wn + nt * 16 + l16;
        bfr[nt] = ld8(&base[TM * 64 + row * 64 + (((ks * 4 + quad) ^ (l16 & 7)) * 8)]);
      }
#pragma unroll
      for (int mt = 0; mt < MT; ++mt)
#pragma unroll
        for (int nt = 0; nt < 4; ++nt)
          acc[mt][nt] =
              __builtin_amdgcn_mfma_f32_16x16x32_bf16(bfr[nt], af[mt], acc[mt][nt], 0, 0, 0);
    }
  };

  if (DB) {
    const int nst = K >> 6;
    stage(0, 0);
    for (int st = 0; st < nst; ++st) {
      __syncthreads();  // drains own DMA(st); all waves done with buf[(st+1)&1]
      if (st + 1 < nst) stage((st + 1) << 6, (st + 1) & 1);
      ktile(lds + (st & 1) * HALF);
    }
  } else {
    for (int kt = 0; kt < K; kt += 64) {
      stage(kt, 0);
      __syncthreads();
      ktile(lds);
      __syncthreads();
    }
  }

  const bool f32 = flag[0] == 0;
#pragma unroll
  for (int mt = 0; mt < MT; ++mt) {
    const int row = m0 + wm + mt * 16 + l16;  // global output row (per lane)
#pragma unroll
    for (int nt = 0; nt < 4; ++nt) {
      const int cb = n0 + wn + nt * 16 + quad * 4;  // 4 consecutive cols
      float v[4];
#pragma unroll
      for (int r = 0; r < 4; ++r) v[r] = acc[mt][nt][r];

      if (EPI == EP_GELU || EPI == EP_BIASRES) {
        float bv[4];
        if (f32) {
          f32x4 bq = *(const f32x4*)((const float*)bias + boff + cb);
#pragma unroll
          for (int r = 0; r < 4; ++r) bv[r] = bq[r];
        } else {
          u32x2 bq = *(const u32x2*)((const u16*)bias + boff + cb);
          bv[0] = bf2f((u16)(bq[0] & 0xffffu));
          bv[1] = bf2f((u16)(bq[0] >> 16));
          bv[2] = bf2f((u16)(bq[1] & 0xffffu));
          bv[3] = bf2f((u16)(bq[1] >> 16));
        }
        if (EPI == EP_GELU) {
#pragma unroll
          for (int r = 0; r < 4; ++r) {
            float x_ = v[r] + bv[r];
            v[r] = 0.5f * x_ * (1.0f + erff(x_ * 0.70710678118654752f));
          }
        } else {
#pragma unroll
          for (int r = 0; r < 4; ++r) v[r] += bv[r];
        }
      }
      if (EPI == EP_RES || EPI == EP_BIASRES) {
        size_t ri = (size_t)row * N + cb;
        if (RESRAW && f32) {
          f32x4 rq = *(const f32x4*)((const float*)res + ri);
#pragma unroll
          for (int r = 0; r < 4; ++r) v[r] += rq[r];
        } else {
          u32x2 rq = *(const u32x2*)((const u16*)res + ri);
          v[0] += bf2f((u16)(rq[0] & 0xffffu));
          v[1] += bf2f((u16)(rq[0] >> 16));
          v[2] += bf2f((u16)(rq[1] & 0xffffu));
          v[3] += bf2f((u16)(rq[1] >> 16));
        }
      }

      if (EPI == EP_QKV) {
        if (cb < 1024) {  // q, pre-scaled by 0.125
          u32x2 pk2 = {cvtpk(v[0] * 0.125f, v[1] * 0.125f),
                       cvtpk(v[2] * 0.125f, v[3] * 0.125f)};
          *(u32x2*)((u16*)Cv + (size_t)row * 1024 + cb) = pk2;
        } else if (cb < 2048) {  // k
          u32x2 pk2 = {cvtpk(v[0], v[1]), cvtpk(v[2], v[3])};
          *(u32x2*)(kout + (size_t)row * 1024 + (cb - 1024)) = pk2;
        } else {  // vT[(b*8+h)*128+d][2048]: d = c2&127 varies with r -> scalar
          int c2 = cb - 2048;
          int bb_ = row >> 11, n = row & 2047, hh = c2 >> 7, d0 = c2 & 127;
#pragma unroll
          for (int r = 0; r < 4; ++r)
            vtout[(size_t)((bb_ * 8 + hh) * 128 + d0 + r) * 2048 + n] = f2bf(v[r]);
        }
      } else {
        size_t ci = (size_t)row * N + cb;
        if (OUTFLEX && f32) {
          f32x4 ov = {v[0], v[1], v[2], v[3]};
          *(f32x4*)((float*)Cv + ci) = ov;
        } else {
          u32x2 pk2 = {cvtpk(v[0], v[1]), cvtpk(v[2], v[3])};
          *(u32x2*)((u16*)Cv + ci) = pk2;
        }
      }
    }
  }
}

// ---- 256^2 GELU GEMM: C = gelu(A*Bt^T + b). 512 thr / 8 waves (2Mx4N),
// BK=64, 128KB dbuf LDS. Same single-barrier DB schedule + XOR swizzle as
// gemm_bt (row stride 128B -> bank-free ds_read_b128). grid (N/256, M/256). ----
__global__ __launch_bounds__(512, 2) void gemm256_gelu(
    const u16* __restrict__ A, const u16* __restrict__ Bt, u16* __restrict__ Cv,
    int M, int N, int K, const void* __restrict__ bias,
    const int* __restrict__ flag) {
  constexpr int HALF = 2 * 256 * 64;  // 32768 u16 per buffer (A 16K + B 16K)
  extern __shared__ __align__(16) u16 lds[];
  const int t = threadIdx.x;
  const int w = t >> 6, L = t & 63;
  const int quad = L >> 4, l16 = L & 15;
  const int m0 = blockIdx.y * 256, n0 = blockIdx.x * 256;
  const int wm = (w >> 2) * 128, wn = (w & 3) * 64;
  const int srow = t >> 3, spc = t & 7;  // srow 0..63, spc 0..7
  const int sc = spc ^ (srow & 7);

  f32x4 acc[8][4] = {};
  const u16* Ab = A + (size_t)m0 * K;
  const u16* Bb = Bt + (size_t)n0 * K;

  auto stage = [&](int kt, int bsel) {
    u16* base = lds + bsel * HALF;
#pragma unroll
    for (int r = 0; r < 4; ++r) {
      int row = r * 64 + srow;  // 0..255
      async16(Ab + (size_t)row * K + kt + sc * 8, &base[row * 64 + spc * 8]);
      async16(Bb + (size_t)row * K + kt + sc * 8, &base[16384 + row * 64 + spc * 8]);
    }
  };
  auto ktile = [&](const u16* base) {
#pragma unroll
    for (int ks = 0; ks < 2; ++ks) {
      bf16x8 af[8], bfr[4];
#pragma unroll
      for (int mt = 0; mt < 8; ++mt) {
        int row = wm + mt * 16 + l16;
        af[mt] = ld8(&base[row * 64 + (((ks * 4 + quad) ^ (l16 & 7)) * 8)]);
      }
#pragma unroll
      for (int nt = 0; nt < 4; ++nt) {
        int row = wn + nt * 16 + l16;
        bfr[nt] = ld8(&base[16384 + row * 64 + (((ks * 4 + quad) ^ (l16 & 7)) * 8)]);
      }
#pragma unroll
      for (int mt = 0; mt < 8; ++mt)
#pragma unroll
        for (int nt = 0; nt < 4; ++nt)
          acc[mt][nt] =
              __builtin_amdgcn_mfma_f32_16x16x32_bf16(bfr[nt], af[mt], acc[mt][nt], 0, 0, 0);
    }
  };

  const int nst = K >> 6;
  stage(0, 0);
  for (int st = 0; st < nst; ++st) {
    __syncthreads();  // drains own DMA(st); all waves done with buf[(st+1)&1]
    if (st + 1 < nst) stage((st + 1) << 6, (st + 1) & 1);
    ktile(lds + (st & 1) * HALF);
  }

  const bool f32 = flag[0] == 0;
#pragma unroll
  for (int mt = 0; mt < 8; ++mt) {
    const int row = m0 + wm + mt * 16 + l16;
#pragma unroll
    for (int nt = 0; nt < 4; ++nt) {
      const int cb = n0 + wn + nt * 16 + quad * 4;
      float bv[4];
      if (f32) {
        f32x4 bq = *(const f32x4*)((const float*)bias + cb);
#pragma unroll
        for (int r = 0; r < 4; ++r) bv[r] = bq[r];
      } else {
        u32x2 bq = *(const u32x2*)((const u16*)bias + cb);
        bv[0] = bf2f((u16)(bq[0] & 0xffffu));
        bv[1] = bf2f((u16)(bq[0] >> 16));
        bv[2] = bf2f((u16)(bq[1] & 0xffffu));
        bv[3] = bf2f((u16)(bq[1] >> 16));
      }
      float v[4];
#pragma unroll
      for (int r = 0; r < 4; ++r) {
        float x_ = acc[mt][nt][r] + bv[r];
        v[r] = 0.5f * x_ * (1.0f + erff(x_ * 0.70710678118654752f));
      }
      u32x2 pk2 = {cvtpk(v[0], v[1]), cvtpk(v[2], v[3])};
      *(u32x2*)(Cv + (size_t)row * N + cb) = pk2;
    }
  }
}

// ---------------- Flash differential attention (8-wave, in-register P) ------------
// grid 512 = b(2) x h(8) x qtile(32 of 64 rows), XCD-remapped. 8 waves (512 thr):
// comp=w>>2, rh=(w&3)*16 (16 q-rows per wave). waves/CU 16 (4/SIMD).
// LDS (u16, 64KB dynamic): K[2buf][2comp][64][64] @0 | V[2buf][128][64] @16384
// Q: per-lane direct global loads. P: in-register via cvt_pk + permlane swaps.
// One __syncthreads per tile; K-loop unrolled x2 (compile-time buffer index).
// Softmax: raw v_exp_f32 with FIXED shift (mst=0); overflow guard on ps
// replaces the row-max reduce (softmax is shift-invariant; guard never fires
// in-dist, rare branch recomputes with true max).
__global__ __launch_bounds__(512, 4) void attn_kernel(
    const u16* __restrict__ q, const u16* __restrict__ k, const u16* __restrict__ vT,
    const float* __restrict__ lamp, const void* __restrict__ subw,
    const int* __restrict__ flag, u16* __restrict__ o) {
  extern __shared__ __align__(16) u16 lds[];
  constexpr int VB = 16384;
  const int t = threadIdx.x, w = t >> 6, L = t & 63;
  const int quad = L >> 4, l16 = L & 15;
  // bijective XCD remap (512 = 8 x 64): XCD x keeps (b,h) pairs {2x,2x+1}
  const int bid = ((blockIdx.x & 7) << 6) | (blockIdx.x >> 3);
  const int qt = bid & 31, h = (bid >> 5) & 7, b = bid >> 8;
  const int q0 = qt * 64;
  const int comp = w >> 2, rh = (w & 3) * 16;
  const int srow = L >> 3, spc = L & 7, sc = spc ^ srow;
  const u16* vb = vT + (size_t)(b * 8 + h) * (128 * 2048);

  auto stageK = [&](int kt, int bsel) {
#pragma unroll
    for (int r = 0; r < 2; ++r) {
      int row = w * 16 + r * 8 + srow;  // 0..127: comp=row>>6, key=row&63
      int c_ = row >> 6, key = row & 63;
      async16(k + ((size_t)(b * 2048 + kt + key) * 1024 + (2 * h + c_) * 64 + sc * 8),
              &lds[bsel * 8192 + row * 64 + spc * 8]);
    }
  };
  auto stageV = [&](int kt, int bsel) {
#pragma unroll
    for (int r = 0; r < 2; ++r) {
      int dim = w * 16 + r * 8 + srow;  // 0..127
      async16(vb + (size_t)dim * 2048 + kt + sc * 8,
              &lds[VB + bsel * 8192 + dim * 64 + spc * 8]);
    }
  };

  stageK(0, 0);
  stageV(0, 0);
  // Q fragments: per-lane direct global loads (one-time; L2-hit). Lane owns
  // qrow = rh + l16 of its comp.
  bf16x8 qf[2];
#pragma unroll
  for (int ks = 0; ks < 2; ++ks) {
    int row = q0 + rh + l16;
    qf[ks] = ld8(q + (size_t)(b * 2048 + row) * 1024 + (2 * h + comp) * 64 +
                 ks * 32 + quad * 8);
  }

  float mst = 0.f, mstl = 0.f, lst = 0.f;
  f32x4 oacc[8] = {};

  // one K/V tile, buffer index bb is a compile-time-foldable constant
  auto tile = [&](int bb) {
    // S^T = Ktile * Q^T for own comp; lane owns qrow = rh + l16
    f32x4 s[4] = {};
#pragma unroll
    for (int ks = 0; ks < 2; ++ks) {
      bf16x8 kf[4];
#pragma unroll
      for (int nt = 0; nt < 4; ++nt) {
        int row = nt * 16 + l16;
        kf[nt] = ld8(&lds[bb * 8192 + comp * 4096 + row * 64 +
                          (((ks * 4 + quad) ^ (l16 & 7)) * 8)]);
      }
#pragma unroll
      for (int nt = 0; nt < 4; ++nt)
        s[nt] = __builtin_amdgcn_mfma_f32_16x16x32_bf16(kf[nt], qf[ks], s[nt], 0, 0, 0);
    }

    // exps with current fixed shift (TRANS pipe; no cross-lane dependency)
    float p[4][4];
#pragma unroll
    for (int nt = 0; nt < 4; ++nt)
#pragma unroll
      for (int r = 0; r < 4; ++r)
        p[nt][r] = fexp2(__builtin_fmaf(s[nt][r], LOG2E, -mstl));

    float ps = 0.f;
#pragma unroll
    for (int nt = 0; nt < 4; ++nt)
#pragma unroll
      for (int r = 0; r < 4; ++r) ps += p[nt][r];

    // overflow guard (replaces the row-max reduce; softmax is shift-invariant)
    if (__ballot(!(ps < 1.0e18f))) {  // wave-uniform; never fires in-dist
      float mx = -3.0e38f;
#pragma unroll
      for (int nt = 0; nt < 4; ++nt)
#pragma unroll
        for (int r = 0; r < 4; ++r) mx = fmaxf(mx, s[nt][r]);
      mx = fmaxf(mx, __shfl_xor(mx, 16));
      mx = fmaxf(mx, __shfl_xor(mx, 32));
      float mnew = fmaxf(mst, mx);
      float al = fexp2((mst - mnew) * LOG2E);
      mst = mnew;
      mstl = mnew * LOG2E;
      lst *= al;
      ps = 0.f;
#pragma unroll
      for (int nt = 0; nt < 4; ++nt)
#pragma unroll
        for (int r = 0; r < 4; ++r) {
          p[nt][r] = fexp2(__builtin_fmaf(s[nt][r], LOG2E, -mstl));
          ps += p[nt][r];
        }
#pragma unroll
      for (int nt = 0; nt < 8; ++nt)
#pragma unroll
        for (int r = 0; r < 4; ++r) oacc[nt][r] *= al;
    }

    u32 wreg[4][2];
#pragma unroll
    for (int nt = 0; nt < 4; ++nt) {
      wreg[nt][0] = cvtpk(p[nt][0], p[nt][1]);
      wreg[nt][1] = cvtpk(p[nt][2], p[nt][3]);
    }
    ps += __shfl_xor(ps, 16);
    ps += __shfl_xor(ps, 32);
    lst += ps;

    // O^T += Vtile^T * P^T ; pf built in-register via permlane swaps
#pragma unroll
    for (int ks = 0; ks < 2; ++ks) {
      u32 a0 = wreg[2 * ks][0], b0 = wreg[2 * ks + 1][0];  // j=0
      u32 a1 = wreg[2 * ks][1], b1 = wreg[2 * ks + 1][1];  // j=1
      asm("v_permlane32_swap_b32 %0, %1" : "+v"(a0), "+v"(b0));
      asm("v_permlane16_swap_b32 %0, %1" : "+v"(a0), "+v"(b0));
      asm("v_permlane32_swap_b32 %0, %1" : "+v"(a1), "+v"(b1));
      asm("v_permlane16_swap_b32 %0, %1" : "+v"(a1), "+v"(b1));
      u32x4 pw = {a0, a1, b0, b1};  // keys base+{0,1},{2,3},{4,5},{6,7}
      bf16x8 pf = __builtin_bit_cast(bf16x8, pw);
#pragma unroll
      for (int nt = 0; nt < 8; ++nt) {
        int dim = nt * 16 + l16;
        bf16x8 vf = ld8(&lds[VB + bb * 8192 + dim * 64 +
                             (((ks * 4 + quad) ^ (l16 & 7)) * 8)]);
        oacc[nt] = __builtin_amdgcn_mfma_f32_16x16x32_bf16(vf, pf, oacc[nt], 0, 0, 0);
      }
    }
  };

  for (int ti = 0; ti < 32; ti += 2) {
    __syncthreads();  // drains own DMA(ti); all waves done reading buf1
    stageK((ti + 1) * 64, 1);
    stageV((ti + 1) * 64, 1);
    tile(0);
    __syncthreads();  // drains own DMA(ti+1); all waves done reading buf0
    if (ti + 2 < 32) {
      stageK((ti + 2) * 64, 0);
      stageV((ti + 2) * 64, 0);
    }
    tile(1);
  }

  // normalize by l (per-lane scalar)
  {
    float inv = 1.0f / lst;
#pragma unroll
    for (int nt = 0; nt < 8; ++nt)
#pragma unroll
      for (int r = 0; r < 4; ++r) oacc[nt][r] *= inv;
  }

  __syncthreads();  // all waves done with K/V -> cb may reuse LDS base
  // combine: comp1 waves dump normalized O2^T (f32x4) to LDS; comp0 diff+RMS+store
  float* cb = (float*)lds;  // 64 rows x 132 floats: cb[qrow][dim] (33.8KB < 64KB)
  if (comp == 1) {
    int rowc = rh + l16;
#pragma unroll
    for (int nt = 0; nt < 8; ++nt)
      *(f32x4*)(&cb[rowc * 132 + nt * 16 + quad * 4]) = oacc[nt];
  }
  __syncthreads();
  if (comp == 0) {
    const bool f32 = flag[0] == 0;
    float lam = lamp[0];
    int rowc = rh + l16;
    float dv[8][4];
    float sq = 0.f;
#pragma unroll
    for (int nt = 0; nt < 8; ++nt) {
      f32x4 c2 = *(const f32x4*)(&cb[rowc * 132 + nt * 16 + quad * 4]);
#pragma unroll
      for (int r = 0; r < 4; ++r) {
        float d = oacc[nt][r] - lam * c2[r];
        dv[nt][r] = d;
        sq += d * d;
      }
    }
    sq += __shfl_xor(sq, 16);
    sq += __shfl_xor(sq, 32);
    float rms = rsqrtf(sq * (1.0f / 128.0f) + 1e-5f);
    size_t rowg = (size_t)(b * 2048 + q0 + rowc) * 1024 + h * 128;
#pragma unroll
    for (int nt = 0; nt < 8; ++nt) {
      float v0 = dv[nt][0] * rms * ldf(subw, nt * 16 + quad * 4 + 0, f32) * ONE_MINUS_LAM_INIT;
      float v1 = dv[nt][1] * rms * ldf(subw, nt * 16 + quad * 4 + 1, f32) * ONE_MINUS_LAM_INIT;
      float v2 = dv[nt][2] * rms * ldf(subw, nt * 16 + quad * 4 + 2, f32) * ONE_MINUS_LAM_INIT;
      float v3 = dv[nt][3] * rms * ldf(subw, nt * 16 + quad * 4 + 3, f32) * ONE_MINUS_LAM_INIT;
      u32x2 pk2 = {cvtpk(v0, v1), cvtpk(v2, v3)};
      *(u32x2*)(o + rowg + nt * 16 + quad * 4) = pk2;
    }
  }
}

// ---------------- host ----------------
extern "C" void kernel_launch(void* const* d_in, const int* in_sizes, int n_in,
                              void* d_out, int out_size, void* d_ws, size_t ws_size,
                              hipStream_t stream) {
  (void)in_sizes; (void)n_in; (void)out_size;
  const void* x = d_in[0];
  const void* ln1w = d_in[1];
  const void* ln1b = d_in[2];
  const void* Wq = d_in[3];
  const void* Wk = d_in[4];
  const void* Wv = d_in[5];
  const void* Wo = d_in[6];
  const void* lq1 = d_in[7];
  const void* lk1 = d_in[8];
  const void* lq2 = d_in[9];
  const void* lk2 = d_in[10];
  const void* subw = d_in[11];
  const void* ln2w = d_in[12];
  const void* ln2b = d_in[13];
  const void* W1 = d_in[14];
  const void* b1 = d_in[15];
  const void* W2 = d_in[16];
  const void* b2 = d_in[17];

  char* ws = (char*)d_ws;
  const size_t MB = 1u << 20;
  u16* A = (u16*)ws;               // h1 -> ob -> h2
  u16* B = (u16*)(ws + 8 * MB);    // q -> g(lo) [fallback]
  u16* C = (u16*)(ws + 16 * MB);   // k -> g(hi) [fallback]
  u16* D = (u16*)(ws + 24 * MB);   // vT -> WoT -> W1T(full or half)|W2Th
  u16* E = (u16*)(ws + 32 * MB);   // WqT|WkT|WvT -> x2
  const bool MERGED = ws_size >= 81 * MB;  // capture-time constant
  u16* gfull = (u16*)(ws + 40 * MB);       // 32MB (merged path)
  u16* W2Tf = (u16*)(ws + 72 * MB);        // 8MB (merged path)
  float* lam = (float*)(MERGED ? ws + 80 * MB : ws + 40 * MB);
  int* flag = (int*)((char*)lam + 64);
  u16* W2Th = D + 2097152;  // fallback per-half W2T (+4MB into D)

  // dynamic-LDS sizes (bytes): gemm HALF = (TM*64 + 128*64)*2
  const int g64_2 = (64 * 64 + 128 * 64) * 2 * 2;   // 49152, double-buffer
  const int g128_2 = (128 * 64 + 128 * 64) * 2 * 2; // 65536, double-buffer
  const int g256_2 = 2 * 2 * 256 * 64 * 2;          // 131072, 256^2 double-buffer

  // 256^2 GELU needs 128KB dynamic LDS: gate on the attribute call succeeding
  static bool big_lds_ok = false;
  static bool big_lds_tried = false;
  if (!big_lds_tried) {
    big_lds_tried = true;
    big_lds_ok = hipFuncSetAttribute((const void*)gemm256_gelu,
                                     hipFuncAttributeMaxDynamicSharedMemorySize,
                                     g256_2) == hipSuccess;
  }

  detect_kernel<<<dim3(1), dim3(64), 0, stream>>>((const u32*)x, flag);
  lam_kernel<<<dim3(1), dim3(64), 0, stream>>>(lq1, lk1, lq2, lk2, flag, lam);
  ln_kernel<true><<<dim3(1024), dim3(256), 0, stream>>>(x, ln1w, ln1b, flag, A);

  // Wq|Wk|Wv -> E concatenated n-major (3072 x 1024)
  twc_kernel<<<dim3(16, 16, 3), dim3(256), 0, stream>>>(Wq, Wk, Wv, E, 1024, 1024, 0,
                                                        1048576, flag);
  // fused q/k/v projection: q->B (pre-scaled), k->C, vT->D
  gemm_bt<128, EP_QKV, false, false, true><<<dim3(24, 32), dim3(256), g128_2, stream>>>(
      A, E, B, 4096, 3072, 1024, nullptr, 0, nullptr, flag, C, D);

  attn_kernel<<<dim3(512), dim3(512), 65536, stream>>>(B, C, D, lam, subw, flag, A);

  // WoT -> D (vT dead); x2(bf16) = ob @ Wo + x -> E (Wq..WvT dead)
  twc_kernel<<<dim3(16, 16, 1), dim3(256), 0, stream>>>(Wo, Wo, Wo, D, 1024, 1024, 0, 0,
                                                        flag);
  gemm_bt<64, EP_RES, true, false, true><<<dim3(8, 64), dim3(256), g64_2, stream>>>(
      A, D, E, 4096, 1024, 1024, nullptr, 0, x, flag, nullptr, nullptr);
  ln_kernel<false><<<dim3(1024), dim3(256), 0, stream>>>(E, ln2w, ln2b, flag, A);

  if (MERGED) {
    // full W1T [4096][1024] -> D (8MB); full W2T [1024][4096] -> W2Tf
    twc_kernel<<<dim3(64, 16, 1), dim3(256), 0, stream>>>(W1, W1, W1, D, 4096, 1024, 0,
                                                          0, flag);
    twc_kernel<<<dim3(16, 64, 1), dim3(256), 0, stream>>>(W2, W2, W2, W2Tf, 1024, 4096,
                                                          0, 0, flag);
    // g = gelu(h2 @ W1 + b1): 256^2 tile (grid 256 = 1 blk/CU) if 128KB LDS ok
    if (big_lds_ok) {
      gemm256_gelu<<<dim3(16, 16), dim3(512), g256_2, stream>>>(
          A, D, gfull, 4096, 4096, 1024, b1, flag);
    } else {
      gemm_bt<128, EP_GELU, false, false, true><<<dim3(32, 32), dim3(256), g128_2,
                                                  stream>>>(
          A, D, gfull, 4096, 4096, 1024, b1, 0, nullptr, flag, nullptr, nullptr);
    }
    // out = g @ W2 + b2 + x2: one full-K launch (M=4096, N=1024, K=4096)
    gemm_bt<64, EP_BIASRES, false, true, true><<<dim3(8, 64), dim3(256), g64_2,
                                                 stream>>>(
        gfull, W2Tf, d_out, 4096, 1024, 4096, b2, 0, E, flag, nullptr, nullptr);
  } else {
    // fallback: FFN in two FF-column halves; g = B..C (16MB contiguous)
    for (int hh = 0; hh < 2; ++hh) {
      twc_kernel<<<dim3(32, 16, 1), dim3(256), 0, stream>>>(W1, W1, W1, D, 4096, 1024,
                                                            (size_t)hh * 2048, 0, flag);
      twc_kernel<<<dim3(16, 32, 1), dim3(256), 0, stream>>>(
          W2, W2, W2, W2Th, 1024, 2048, (size_t)hh * 2048 * 1024, 0, flag);
      gemm_bt<128, EP_GELU, false, false, true><<<dim3(16, 32), dim3(256), g128_2,
                                                  stream>>>(
          A, D, B, 4096, 2048, 1024, b1, hh * 2048, nullptr, flag, nullptr, nullptr);
      if (hh == 0) {
        gemm_bt<64, EP_BIASRES, false, true, true><<<dim3(8, 64), dim3(256), g64_2,
                                                     stream>>>(
            B, W2Th, d_out, 4096, 1024, 2048, b2, 0, E, flag, nullptr, nullptr);
      } else {
        gemm_bt<64, EP_RES, true, true, true><<<dim3(8, 64), dim3(256), g64_2,
                                                stream>>>(
            B, W2Th, d_out, 4096, 1024, 2048, nullptr, 0, d_out, flag, nullptr,
            nullptr);
      }
    }
  }
}